// Round 4
// baseline (159.366 us; speedup 1.0000x reference)
//
#include <hip/hip_runtime.h>
#include <hip/hip_bf16.h>

// StructuralAttention v4: algebraic fusion, spill-free, transpose-free inner loop.
//   S_eff = X*M*X^T + 1*v^T,  M = Wq^T Wk / sqrt(d)   (row-const terms cancel in softmax)
//   v     = X*(Wk^T bq)/sqrt(d)
//   O     = (P*X)*Wv^T / rowsum(P) + bv               (K,V never materialized)
// Pre-kernel -> d_ws: Mt bf16[128][128] (M^T row-major), w f32[128], Wvb bf16[128][128].
// Main: 1 block = 1024 thr (16 waves) per graph; each wave owns ONE 16-row q-tile.
// LDS 129 KB: Xs bf16[256][128] + XsT bf16[128][256] + v f32[256] -> 1 block/CU,
// 16 waves/CU. Peak live regs ~80 < 128 cap ((1024,4) = 4 waves/EU). Mt and Wvb
// fragments are read straight from global (L2-resident, shared by all 512 blocks).
// ONE __syncthreads total.

typedef float f32x4 __attribute__((ext_vector_type(4)));
typedef unsigned int u32x2 __attribute__((ext_vector_type(2)));
typedef unsigned int u32x4 __attribute__((ext_vector_type(4)));
typedef short s16x4 __attribute__((ext_vector_type(4)));
typedef short s16x8 __attribute__((ext_vector_type(8)));

#define SCALE 0.088388347648318447f  // 1/sqrt(128)
#define XT0   65536                  // XsT bf16[128][256]
#define VOFF  131072                 // v f32[256]
#define LDSSZ 132096
#define WOFF  32768                  // w f32[128] in ws
#define WVB   33280                  // Wvb bf16[128][128] in ws

__device__ __forceinline__ unsigned short bf16s(float a) {
    return __builtin_bit_cast(unsigned short, __float2bfloat16(a));  // RNE
}
__device__ __forceinline__ unsigned bf16pk(float a, float b) {
    return (unsigned)bf16s(a) | ((unsigned)bf16s(b) << 16);
}
__device__ __forceinline__ f32x4 mfma16(u32x2 a, u32x2 b, f32x4 c) {
    return __builtin_amdgcn_mfma_f32_16x16x16bf16_1k(
        __builtin_bit_cast(s16x4, a), __builtin_bit_cast(s16x4, b), c, 0, 0, 0);
}
__device__ __forceinline__ f32x4 mfma32(u32x4 a, u32x4 b, f32x4 c) {
    return __builtin_amdgcn_mfma_f32_16x16x32_bf16(
        __builtin_bit_cast(s16x8, a), __builtin_bit_cast(s16x8, b), c, 0, 0, 0);
}

// Xs: bf16[256][128] row-major; reads hit 16 distinct rows -> XOR spreads across banks
__device__ __forceinline__ int ks_off(int row, int d) {
    return (row << 8) + ((d << 1) ^ ((row & 15) << 3));
}
// XsT: bf16[128][256] row-major (row = d-feature, col = node k)
__device__ __forceinline__ int xst_off(int row, int k) {
    return XT0 + (row << 9) + ((k << 1) ^ ((row & 15) << 3));
}

// ---------------- precompute: Mt bf16 + w f32 + Wvb bf16 -> d_ws ----------------
extern "C" __global__ void __launch_bounds__(256)
sattn_pre(const float* __restrict__ Wq, const float* __restrict__ bq,
          const float* __restrict__ Wk, const float* __restrict__ Wv,
          char* __restrict__ wsb)
{
    const int b = blockIdx.x, t = threadIdx.x;
    if (b < 64) {
        const int row = b * 2 + (t >> 7);   // Mt row = "k-side" feature
        const int a   = t & 127;
        float acc = 0.f;
#pragma unroll 4
        for (int o = 0; o < 128; ++o)
            acc += Wq[o * 128 + a] * Wk[o * 128 + row];
        *(unsigned short*)(wsb + (row << 8) + (a << 1)) = bf16s(acc * SCALE);
    } else if (b == 64) {
        if (t < 128) {
            float acc = 0.f;
#pragma unroll 4
            for (int o = 0; o < 128; ++o)
                acc += bq[o] * Wk[o * 128 + t];
            *(float*)(wsb + WOFF + 4 * t) = acc * SCALE;
        }
    } else {
        const int row = (b - 65) * 2 + (t >> 7);
        const int col = t & 127;
        *(unsigned short*)(wsb + WVB + (row << 8) + (col << 1)) =
            bf16s(Wv[row * 128 + col]);
    }
}

// ---------------- main fused kernel: 1 block (16 waves) per graph ----------------
extern "C" __global__ void __launch_bounds__(1024, 4)
sattn(const float* __restrict__ x, const float* __restrict__ bv,
      const char* __restrict__ wsb, float* __restrict__ out)
{
    extern __shared__ char sm[];
    const int t    = threadIdx.x;
    const int lane = t & 63;
    const int w    = t >> 6;        // wave 0..15
    const int h    = lane & 15;
    const int g    = lane >> 4;
    const int R0   = blockIdx.x << 8;
    const int wq0  = w << 4;        // wave's q-tile base row
    const f32x4 Z  = {0.f, 0.f, 0.f, 0.f};

    // -- phase A: load X rows wq0+h (fp32 -> bf16 frags) + v = X*w partial --
    u32x2 xf[8];
    float vp = 0.f;
    {
        const float* wvec = (const float*)(wsb + WOFF);
        const float* xr = x + (size_t)(R0 + wq0 + h) * 128 + 4 * g;
#pragma unroll
        for (int c = 0; c < 8; ++c) {
            f32x4 v4 = *(const f32x4*)(xr + 16 * c);
            f32x4 wc = *(const f32x4*)(wvec + 16 * c + 4 * g);
            vp += v4.x * wc.x + v4.y * wc.y + v4.z * wc.z + v4.w * wc.w;
            xf[c] = (u32x2){ bf16pk(v4.x, v4.y), bf16pk(v4.z, v4.w) };
        }
    }
    vp += __shfl_xor(vp, 16); vp += __shfl_xor(vp, 32);
    if (g == 0) *(float*)(sm + VOFF + (wq0 + h) * 4) = vp;

    // -- Y^T fragments: Y^T = Mt * X^T, Mt straight from global (L2) --
    u32x2 yf[8];   // yf[jt]: lane h holds Y[q=wq0+h][b=16jt+4g+i]
#pragma unroll
    for (int jt = 0; jt < 8; ++jt) {
        f32x4 a = Z;
#pragma unroll
        for (int c2 = 0; c2 < 4; ++c2) {
            const char* mp = wsb + ((h + 16 * jt) << 8) + ((32 * c2 + 4 * g) << 1);
            u32x2 mlo = *(const u32x2*)mp;
            u32x2 mhi = *(const u32x2*)(mp + 32);
            u32x4 A = (u32x4){ mlo.x, mlo.y, mhi.x, mhi.y };
            u32x4 B = (u32x4){ xf[2 * c2].x, xf[2 * c2].y, xf[2 * c2 + 1].x, xf[2 * c2 + 1].y };
            a = mfma32(A, B, a);
        }
        yf[jt] = (u32x2){ bf16pk(a.x, a.y), bf16pk(a.z, a.w) };
    }

    // identity B-fragment for transpose-MFMAs: B[k=4g+i][col=h] = (4g+i==h)
    const int ii = h - 4 * g;
    u32x2 idf;
    idf.x = (ii == 0 ? 0x3F80u : 0u) | (ii == 1 ? (0x3F80u << 16) : 0u);
    idf.y = (ii == 2 ? 0x3F80u : 0u) | (ii == 3 ? (0x3F80u << 16) : 0u);

    // -- write Xs rows; build XsT subtiles from xf via identity-MFMA transpose --
#pragma unroll
    for (int c = 0; c < 8; ++c)
        *(u32x2*)(sm + ks_off(wq0 + h, 16 * c + 4 * g)) = xf[c];
#pragma unroll
    for (int c = 0; c < 8; ++c) {
        f32x4 ta = mfma16(xf[c], idf, Z);   // lane h reg r = X[wq0+4g+r][16c+h]
        *(u32x2*)(sm + xst_off(16 * c + h, wq0 + 4 * g)) =
            (u32x2){ bf16pk(ta.x, ta.y), bf16pk(ta.z, ta.w) };
    }
    __syncthreads();   // Xs + XsT + v visible (the only barrier)

    // -- main loop: S^T tile = Xs*yf ; P = exp(S+v); T^T += pa * XsT --
    f32x4 Tacc[8];     // Tacc[jt]: lane h reg r = T[q=wq0+4g+r][d=16jt+h]
#pragma unroll
    for (int jt = 0; jt < 8; ++jt) Tacc[jt] = Z;
    float ls = 0.f;

#pragma unroll 1
    for (int kc2 = 0; kc2 < 8; ++kc2) {
        u32x2 pk2[2];
#pragma unroll
        for (int kk = 0; kk < 2; ++kk) {
            const int kc = 2 * kc2 + kk;
            f32x4 a = Z;
#pragma unroll
            for (int c2 = 0; c2 < 4; ++c2) {
                u32x2 xlo = *(const u32x2*)(sm + ks_off(16 * kc + h, 32 * c2 + 4 * g));
                u32x2 xhi = *(const u32x2*)(sm + ks_off(16 * kc + h, 32 * c2 + 16 + 4 * g));
                u32x4 A = (u32x4){ xlo.x, xlo.y, xhi.x, xhi.y };
                u32x4 B = (u32x4){ yf[2 * c2].x, yf[2 * c2].y,
                                   yf[2 * c2 + 1].x, yf[2 * c2 + 1].y };
                a = mfma32(A, B, a);   // lane h reg r = S[k=16kc+4g+r][q=wq0+h]
            }
            f32x4 vv = *(const f32x4*)(sm + VOFF + (16 * kc + 4 * g) * 4);
            float e0 = __expf(a.x + vv.x), e1 = __expf(a.y + vv.y);
            float e2 = __expf(a.z + vv.z), e3 = __expf(a.w + vv.w);
            ls += e0 + e1 + e2 + e3;
            pk2[kk] = (u32x2){ bf16pk(e0, e1), bf16pk(e2, e3) };
        }
        u32x4 pa = (u32x4){ pk2[0].x, pk2[0].y, pk2[1].x, pk2[1].y };
#pragma unroll
        for (int jt = 0; jt < 8; ++jt) {
            u32x2 xtlo = *(const u32x2*)(sm + xst_off(16 * jt + h, 32 * kc2 + 4 * g));
            u32x2 xthi = *(const u32x2*)(sm + xst_off(16 * jt + h, 32 * kc2 + 16 + 4 * g));
            u32x4 B = (u32x4){ xtlo.x, xtlo.y, xthi.x, xthi.y };
            Tacc[jt] = mfma32(pa, B, Tacc[jt]);
        }
    }
    ls += __shfl_xor(ls, 16); ls += __shfl_xor(ls, 32);
    const float li = 1.0f / ls;   // inverse row-sum for q = wq0 + h

    // -- transpose-pack Tacc -> T^T B-fragments (register-only) --
    u32x4 tBO[4];
#pragma unroll
    for (int c2 = 0; c2 < 4; ++c2) {
        u32x2 p0 = (u32x2){ bf16pk(Tacc[2 * c2].x, Tacc[2 * c2].y),
                            bf16pk(Tacc[2 * c2].z, Tacc[2 * c2].w) };
        u32x2 p1 = (u32x2){ bf16pk(Tacc[2 * c2 + 1].x, Tacc[2 * c2 + 1].y),
                            bf16pk(Tacc[2 * c2 + 1].z, Tacc[2 * c2 + 1].w) };
        f32x4 d0 = mfma16(p0, idf, Z);   // lane h reg r = T[q=wq0+h][d=32c2+4g+r]
        f32x4 d1 = mfma16(p1, idf, Z);   // ... d=32c2+16+4g+r
        tBO[c2] = (u32x4){ bf16pk(d0.x, d0.y), bf16pk(d0.z, d0.w),
                           bf16pk(d1.x, d1.y), bf16pk(d1.z, d1.w) };
    }

    // -- O^T = Wvb * T^T (Wvb fragments from global/L2); normalize + bias; store --
#pragma unroll
    for (int ot = 0; ot < 8; ++ot) {
        f32x4 o = Z;
#pragma unroll
        for (int c2 = 0; c2 < 4; ++c2) {
            const char* wp = wsb + WVB + ((h + 16 * ot) << 8) + ((32 * c2 + 4 * g) << 1);
            u32x2 wlo = *(const u32x2*)wp;
            u32x2 whi = *(const u32x2*)(wp + 32);
            u32x4 A = (u32x4){ wlo.x, wlo.y, whi.x, whi.y };
            o = mfma32(A, tBO[c2], o);   // lane h reg r = O^T[16ot+4g+r][q=wq0+h]
        }
        f32x4 bvv = *(const f32x4*)(bv + 16 * ot + 4 * g);
        f32x4 r;
#pragma unroll
        for (int j = 0; j < 4; ++j) r[j] = o[j] * li + bvv[j];
        *(f32x4*)(out + (size_t)(R0 + wq0 + h) * 128 + 16 * ot + 4 * g) = r;
    }
}

extern "C" void kernel_launch(void* const* d_in, const int* in_sizes, int n_in,
                              void* d_out, int out_size, void* d_ws, size_t ws_size,
                              hipStream_t stream) {
    const float* x  = (const float*)d_in[0];
    const float* Wq = (const float*)d_in[2];
    const float* bq = (const float*)d_in[3];
    const float* Wk = (const float*)d_in[4];
    const float* Wv = (const float*)d_in[6];
    const float* bv = (const float*)d_in[7];
    float* out = (float*)d_out;
    char* wsb = (char*)d_ws;

    hipFuncSetAttribute((const void*)sattn,
                        hipFuncAttributeMaxDynamicSharedMemorySize, LDSSZ);

    sattn_pre<<<dim3(129), dim3(256), 0, stream>>>(Wq, bq, Wk, Wv, wsb);
    sattn<<<dim3(512), dim3(1024), LDSSZ, stream>>>(x, bv, wsb, out);
}

// Round 5
// 107.566 us; speedup vs baseline: 1.4816x; 1.4816x over previous
//
#include <hip/hip_runtime.h>
#include <hip/hip_bf16.h>

// StructuralAttention v5: v4 algebra + layout in R1's register regime.
//   S_eff = X*M*X^T + 1*v^T,  M = Wq^T Wk / sqrt(d)
//   v     = X*(Wk^T bq)/sqrt(d)
//   O     = (P*X)*Wv^T / rowsum(P) + bv
// Pre-kernel -> d_ws: Mt bf16[128][128], w f32[128], Wvb bf16[128][128].
// Main: 512 thr (8 waves) per graph, __launch_bounds__(512,2) = 256 regs/wave
// (R1's proven spill-free regime; v2-v4 all died of 128-cap register starvation).
// Each wave owns TWO 16-row q-tiles; dual q-tiles share all S-step A-fragment
// reads and all T-step XsT B-fragment reads. LDS 129 KB (Xs + XsT + v) -> 1
// block/CU, 8 waves/CU. Mt/Wvb fragments from global (L2-resident). One barrier.

typedef float f32x4 __attribute__((ext_vector_type(4)));
typedef unsigned int u32x2 __attribute__((ext_vector_type(2)));
typedef unsigned int u32x4 __attribute__((ext_vector_type(4)));
typedef short s16x4 __attribute__((ext_vector_type(4)));
typedef short s16x8 __attribute__((ext_vector_type(8)));

#define SCALE 0.088388347648318447f  // 1/sqrt(128)
#define XT0   65536                  // XsT bf16[128][256]
#define VOFF  131072                 // v f32[256]
#define LDSSZ 132096
#define WOFF  32768                  // w f32[128] in ws
#define WVB   33280                  // Wvb bf16[128][128] in ws

__device__ __forceinline__ unsigned short bf16s(float a) {
    return __builtin_bit_cast(unsigned short, __float2bfloat16(a));  // RNE
}
__device__ __forceinline__ unsigned bf16pk(float a, float b) {
    return (unsigned)bf16s(a) | ((unsigned)bf16s(b) << 16);
}
__device__ __forceinline__ f32x4 mfma16(u32x2 a, u32x2 b, f32x4 c) {
    return __builtin_amdgcn_mfma_f32_16x16x16bf16_1k(
        __builtin_bit_cast(s16x4, a), __builtin_bit_cast(s16x4, b), c, 0, 0, 0);
}
__device__ __forceinline__ f32x4 mfma32(u32x4 a, u32x4 b, f32x4 c) {
    return __builtin_amdgcn_mfma_f32_16x16x32_bf16(
        __builtin_bit_cast(s16x8, a), __builtin_bit_cast(s16x8, b), c, 0, 0, 0);
}

// Xs: bf16[256][128] row-major + XOR swizzle
__device__ __forceinline__ int ks_off(int row, int d) {
    return (row << 8) + ((d << 1) ^ ((row & 15) << 3));
}
// XsT: bf16[128][256] row-major (row = d-feature, col = node)
__device__ __forceinline__ int xst_off(int row, int k) {
    return XT0 + (row << 9) + ((k << 1) ^ ((row & 15) << 3));
}

// ---------------- precompute: Mt bf16 + w f32 + Wvb bf16 -> d_ws ----------------
extern "C" __global__ void __launch_bounds__(256)
sattn_pre(const float* __restrict__ Wq, const float* __restrict__ bq,
          const float* __restrict__ Wk, const float* __restrict__ Wv,
          char* __restrict__ wsb)
{
    const int b = blockIdx.x, t = threadIdx.x;
    if (b < 64) {
        const int row = b * 2 + (t >> 7);
        const int a   = t & 127;
        float acc = 0.f;
#pragma unroll 4
        for (int o = 0; o < 128; ++o)
            acc += Wq[o * 128 + a] * Wk[o * 128 + row];
        *(unsigned short*)(wsb + (row << 8) + (a << 1)) = bf16s(acc * SCALE);
    } else if (b == 64) {
        if (t < 128) {
            float acc = 0.f;
#pragma unroll 4
            for (int o = 0; o < 128; ++o)
                acc += bq[o] * Wk[o * 128 + t];
            *(float*)(wsb + WOFF + 4 * t) = acc * SCALE;
        }
    } else {
        const int row = (b - 65) * 2 + (t >> 7);
        const int col = t & 127;
        *(unsigned short*)(wsb + WVB + (row << 8) + (col << 1)) =
            bf16s(Wv[row * 128 + col]);
    }
}

// ---------------- main fused kernel: 1 block (8 waves) per graph ----------------
extern "C" __global__ void __launch_bounds__(512, 2)
sattn(const float* __restrict__ x, const float* __restrict__ bv,
      const char* __restrict__ wsb, float* __restrict__ out)
{
    extern __shared__ char sm[];
    const int t    = threadIdx.x;
    const int lane = t & 63;
    const int w    = t >> 6;        // wave 0..7
    const int h    = lane & 15;
    const int g    = lane >> 4;
    const int R0   = blockIdx.x << 8;
    const int wr0  = w << 5;        // wave's 32-row slab
    const f32x4 Z  = {0.f, 0.f, 0.f, 0.f};

    // -- phase A: load X rows (fp32 -> bf16 frags) + v = X*w partials --
    u32x2 xf[2][8];
    float vp0 = 0.f, vp1 = 0.f;
    {
        const float* wvec = (const float*)(wsb + WOFF);
#pragma unroll
        for (int rt = 0; rt < 2; ++rt) {
            const float* xr = x + (size_t)(R0 + wr0 + 16 * rt + h) * 128 + 4 * g;
            float vacc = 0.f;
#pragma unroll
            for (int c = 0; c < 8; ++c) {
                f32x4 v4 = *(const f32x4*)(xr + 16 * c);
                f32x4 wc = *(const f32x4*)(wvec + 16 * c + 4 * g);
                vacc += v4.x * wc.x + v4.y * wc.y + v4.z * wc.z + v4.w * wc.w;
                xf[rt][c] = (u32x2){ bf16pk(v4.x, v4.y), bf16pk(v4.z, v4.w) };
            }
            if (rt == 0) vp0 = vacc; else vp1 = vacc;
        }
    }
    vp0 += __shfl_xor(vp0, 16); vp0 += __shfl_xor(vp0, 32);
    vp1 += __shfl_xor(vp1, 16); vp1 += __shfl_xor(vp1, 32);
    if (g == 0) {
        *(float*)(sm + VOFF + (wr0 + h) * 4)      = vp0;
        *(float*)(sm + VOFF + (wr0 + 16 + h) * 4) = vp1;
    }

    // -- Y^T fragments: Y^T = Mt * X^T, Mt straight from global (L2) --
    u32x2 yf[8][2];   // yf[jt][qt]: lane h holds Y[q=wr0+16qt+h][16jt+4g+i]
#pragma unroll
    for (int jt = 0; jt < 8; ++jt) {
        f32x4 a0 = Z, a1 = Z;
#pragma unroll
        for (int c2 = 0; c2 < 4; ++c2) {
            const char* mp = wsb + ((h + 16 * jt) << 8) + ((32 * c2 + 4 * g) << 1);
            u32x2 mlo = *(const u32x2*)mp;
            u32x2 mhi = *(const u32x2*)(mp + 32);
            u32x4 A = (u32x4){ mlo.x, mlo.y, mhi.x, mhi.y };
            u32x4 B0 = (u32x4){ xf[0][2 * c2].x, xf[0][2 * c2].y,
                                xf[0][2 * c2 + 1].x, xf[0][2 * c2 + 1].y };
            u32x4 B1 = (u32x4){ xf[1][2 * c2].x, xf[1][2 * c2].y,
                                xf[1][2 * c2 + 1].x, xf[1][2 * c2 + 1].y };
            a0 = mfma32(A, B0, a0);
            a1 = mfma32(A, B1, a1);
        }
        yf[jt][0] = (u32x2){ bf16pk(a0.x, a0.y), bf16pk(a0.z, a0.w) };
        yf[jt][1] = (u32x2){ bf16pk(a1.x, a1.y), bf16pk(a1.z, a1.w) };
    }

    // identity B-fragment for transpose-MFMAs: B[k=4g+i][col=h] = (4g+i==h)
    const int ii = h - 4 * g;
    u32x2 idf;
    idf.x = (ii == 0 ? 0x3F80u : 0u) | (ii == 1 ? (0x3F80u << 16) : 0u);
    idf.y = (ii == 2 ? 0x3F80u : 0u) | (ii == 3 ? (0x3F80u << 16) : 0u);

    // -- write Xs rows; build XsT subtiles from xf via identity-MFMA transpose --
#pragma unroll
    for (int rt = 0; rt < 2; ++rt) {
#pragma unroll
        for (int c = 0; c < 8; ++c)
            *(u32x2*)(sm + ks_off(wr0 + 16 * rt + h, 16 * c + 4 * g)) = xf[rt][c];
#pragma unroll
        for (int c = 0; c < 8; ++c) {
            f32x4 ta = mfma16(xf[rt][c], idf, Z);  // lane h reg r = X[wr0+16rt+4g+r][16c+h]
            *(u32x2*)(sm + xst_off(16 * c + h, wr0 + 16 * rt + 4 * g)) =
                (u32x2){ bf16pk(ta.x, ta.y), bf16pk(ta.z, ta.w) };
        }
    }
    __syncthreads();   // Xs + XsT + v visible (the only barrier)

    // -- main loop: S^T tiles for both q-tiles share A-frags; T^T shares B-frags --
    f32x4 Tacc[8][2];
#pragma unroll
    for (int jt = 0; jt < 8; ++jt) { Tacc[jt][0] = Z; Tacc[jt][1] = Z; }
    float ls0 = 0.f, ls1 = 0.f;

#pragma unroll 1
    for (int kc2 = 0; kc2 < 8; ++kc2) {
        u32x2 pk0[2], pk1[2];
#pragma unroll
        for (int kk = 0; kk < 2; ++kk) {
            const int kc = 2 * kc2 + kk;
            f32x4 a0 = Z, a1 = Z;
#pragma unroll
            for (int c2 = 0; c2 < 4; ++c2) {
                u32x2 xlo = *(const u32x2*)(sm + ks_off(16 * kc + h, 32 * c2 + 4 * g));
                u32x2 xhi = *(const u32x2*)(sm + ks_off(16 * kc + h, 32 * c2 + 16 + 4 * g));
                u32x4 A = (u32x4){ xlo.x, xlo.y, xhi.x, xhi.y };
                u32x4 B0 = (u32x4){ yf[2 * c2][0].x, yf[2 * c2][0].y,
                                    yf[2 * c2 + 1][0].x, yf[2 * c2 + 1][0].y };
                u32x4 B1 = (u32x4){ yf[2 * c2][1].x, yf[2 * c2][1].y,
                                    yf[2 * c2 + 1][1].x, yf[2 * c2 + 1][1].y };
                a0 = mfma32(A, B0, a0);   // lane h reg r = S[k=16kc+4g+r][q=wr0+h]
                a1 = mfma32(A, B1, a1);   // ... q=wr0+16+h
            }
            f32x4 vv = *(const f32x4*)(sm + VOFF + (16 * kc + 4 * g) * 4);
            float e0 = __expf(a0.x + vv.x), e1 = __expf(a0.y + vv.y);
            float e2 = __expf(a0.z + vv.z), e3 = __expf(a0.w + vv.w);
            float f0 = __expf(a1.x + vv.x), f1 = __expf(a1.y + vv.y);
            float f2 = __expf(a1.z + vv.z), f3 = __expf(a1.w + vv.w);
            ls0 += e0 + e1 + e2 + e3;
            ls1 += f0 + f1 + f2 + f3;
            pk0[kk] = (u32x2){ bf16pk(e0, e1), bf16pk(e2, e3) };
            pk1[kk] = (u32x2){ bf16pk(f0, f1), bf16pk(f2, f3) };
        }
        u32x4 pa0 = (u32x4){ pk0[0].x, pk0[0].y, pk0[1].x, pk0[1].y };
        u32x4 pa1 = (u32x4){ pk1[0].x, pk1[0].y, pk1[1].x, pk1[1].y };
#pragma unroll
        for (int jt = 0; jt < 8; ++jt) {
            u32x2 xtlo = *(const u32x2*)(sm + xst_off(16 * jt + h, 32 * kc2 + 4 * g));
            u32x2 xthi = *(const u32x2*)(sm + xst_off(16 * jt + h, 32 * kc2 + 16 + 4 * g));
            u32x4 B = (u32x4){ xtlo.x, xtlo.y, xthi.x, xthi.y };
            Tacc[jt][0] = mfma32(pa0, B, Tacc[jt][0]);
            Tacc[jt][1] = mfma32(pa1, B, Tacc[jt][1]);
        }
    }
    ls0 += __shfl_xor(ls0, 16); ls0 += __shfl_xor(ls0, 32);
    ls1 += __shfl_xor(ls1, 16); ls1 += __shfl_xor(ls1, 32);
    const float li0 = 1.0f / ls0;   // for q = wr0 + h
    const float li1 = 1.0f / ls1;   // for q = wr0 + 16 + h

    // -- transpose-pack Tacc -> T^T B-fragments (register-only) --
    u32x4 tBO[4][2];
#pragma unroll
    for (int c2 = 0; c2 < 4; ++c2) {
#pragma unroll
        for (int qt = 0; qt < 2; ++qt) {
            f32x4 A0 = Tacc[2 * c2][qt], A1 = Tacc[2 * c2 + 1][qt];
            u32x2 p0 = (u32x2){ bf16pk(A0.x, A0.y), bf16pk(A0.z, A0.w) };
            u32x2 p1 = (u32x2){ bf16pk(A1.x, A1.y), bf16pk(A1.z, A1.w) };
            f32x4 d0 = mfma16(p0, idf, Z);   // lane h reg r = T[q][d=32c2+4g+r]
            f32x4 d1 = mfma16(p1, idf, Z);   // ... d=32c2+16+4g+r
            tBO[c2][qt] = (u32x4){ bf16pk(d0.x, d0.y), bf16pk(d0.z, d0.w),
                                   bf16pk(d1.x, d1.y), bf16pk(d1.z, d1.w) };
        }
    }

    // -- O^T = Wvb * T^T (Wvb from global/L2); normalize + bias; f32x4 stores --
#pragma unroll
    for (int ot = 0; ot < 8; ++ot) {
        f32x4 o0 = Z, o1 = Z;
#pragma unroll
        for (int c2 = 0; c2 < 4; ++c2) {
            const char* wp = wsb + WVB + ((h + 16 * ot) << 8) + ((32 * c2 + 4 * g) << 1);
            u32x2 wlo = *(const u32x2*)wp;
            u32x2 whi = *(const u32x2*)(wp + 32);
            u32x4 A = (u32x4){ wlo.x, wlo.y, whi.x, whi.y };
            o0 = mfma32(A, tBO[c2][0], o0);
            o1 = mfma32(A, tBO[c2][1], o1);
        }
        f32x4 bvv = *(const f32x4*)(bv + 16 * ot + 4 * g);
        f32x4 r0, r1;
#pragma unroll
        for (int j = 0; j < 4; ++j) {
            r0[j] = o0[j] * li0 + bvv[j];
            r1[j] = o1[j] * li1 + bvv[j];
        }
        *(f32x4*)(out + (size_t)(R0 + wr0 + h) * 128 + 16 * ot + 4 * g)      = r0;
        *(f32x4*)(out + (size_t)(R0 + wr0 + 16 + h) * 128 + 16 * ot + 4 * g) = r1;
    }
}

extern "C" void kernel_launch(void* const* d_in, const int* in_sizes, int n_in,
                              void* d_out, int out_size, void* d_ws, size_t ws_size,
                              hipStream_t stream) {
    const float* x  = (const float*)d_in[0];
    const float* Wq = (const float*)d_in[2];
    const float* bq = (const float*)d_in[3];
    const float* Wk = (const float*)d_in[4];
    const float* Wv = (const float*)d_in[6];
    const float* bv = (const float*)d_in[7];
    float* out = (float*)d_out;
    char* wsb = (char*)d_ws;

    hipFuncSetAttribute((const void*)sattn,
                        hipFuncAttributeMaxDynamicSharedMemorySize, LDSSZ);

    sattn_pre<<<dim3(129), dim3(256), 0, stream>>>(Wq, bq, Wk, Wv, wsb);
    sattn<<<dim3(512), dim3(512), LDSSZ, stream>>>(x, bv, wsb, out);
}